// Round 6
// baseline (176.146 us; speedup 1.0000x reference)
//
#include <hip/hip_runtime.h>
#include <cstdint>
#include <cstddef>

// Problem constants
#define NCLUS 64
#define DIM   128
#define BATCH 512              // K of the Gram reduction (bytes per fp8 row)
#define QCOLS 8192             // NCLUS*DIM
#define NPAIR 2016             // 64*63/2
#define TSTRB (QCOLS * BATCH)  // BYTES per tensor in fp8 (4,194,304)
#define FP8SCALE 256.0f        // q^2 * 256 -> e4m3 (max 256 < 448, no clip)

typedef float f32x4 __attribute__((ext_vector_type(4)));
typedef long  lx2  __attribute__((ext_vector_type(2)));

// q2t layout: row (t, c*128+d) of 512 bytes over b. Within each 64-byte
// k-chunk, 8-byte units are PERMUTED: global unit u stored at p=(u&3)*2+(u>>2),
// so one 16-B LDS chunk = both ksteps of one MFMA-quarter (ds_read_b128).

__device__ __forceinline__ void ld_lds16(const void* g, void* l) {
  __builtin_amdgcn_global_load_lds(
      (__attribute__((address_space(1))) void*)g,
      (__attribute__((address_space(3))) void*)l, 16, 0, 0);
}

// ONE fused sync point per K-slot: wait chunk m landed (vmcnt) AND all waves'
// frag reads of iter m-1 done (lgkmcnt) -> safe to overwrite oldest buffer.
#define SYNC_VM4L() asm volatile("s_waitcnt vmcnt(4) lgkmcnt(0)\n\ts_barrier" ::: "memory")
#define SYNC_VM0L() asm volatile("s_waitcnt vmcnt(0) lgkmcnt(0)\n\ts_barrier" ::: "memory")

// ---------------------------------------------------------------------------
// Kernel 1: softmax over D=128, q^2*256 -> fp8 e4m3, permuted-transposed write.
// Block (bq8, c): 64 b's x 2 tensors; 4 threads/row. Full 64-B lines per block.
// ---------------------------------------------------------------------------
__global__ __launch_bounds__(256) void softmax_q2_kernel(
    const float* __restrict__ emb, uint8_t* __restrict__ q2t,
    float* __restrict__ dotPart) {
  __shared__ unsigned short T[2][64][130];   // fp8 byte in low byte
  __shared__ float red[4];
  const int c   = blockIdx.y;
  const int bq8 = blockIdx.x;
  const int tid = threadIdx.x;
  const int w = tid >> 6, lane = tid & 63;
  const int bl = tid >> 2;                   // 0..63 local b
  const int qd = tid & 3;                    // d-range qd*32..+32
  const int b = bq8 * 64 + bl;

  float qa[32];
  float dot = 0.f;
#pragma unroll
  for (int t = 0; t < 2; ++t) {
    const float4* rp = (const float4*)(emb + ((size_t)(t * BATCH + b) * QCOLS +
                                              (size_t)c * DIM + qd * 32));
    float f[32];
#pragma unroll
    for (int u = 0; u < 8; ++u) {
      float4 v = rp[u];
      f[4*u] = v.x; f[4*u+1] = v.y; f[4*u+2] = v.z; f[4*u+3] = v.w;
    }
    float mx = f[0];
#pragma unroll
    for (int j = 1; j < 32; ++j) mx = fmaxf(mx, f[j]);
    mx = fmaxf(mx, __shfl_xor(mx, 1));
    mx = fmaxf(mx, __shfl_xor(mx, 2));
    float s = 0.f;
#pragma unroll
    for (int j = 0; j < 32; ++j) { f[j] = __expf(f[j] - mx); s += f[j]; }
    s += __shfl_xor(s, 1);
    s += __shfl_xor(s, 2);
    float inv = 1.0f / s;
    uint32_t* Tu = (uint32_t*)&T[t][bl][qd * 32];
#pragma unroll
    for (int j = 0; j < 32; j += 2) {
      float q0 = f[j] * inv, q1 = f[j + 1] * inv;
      if (t == 0) { qa[j] = q0; qa[j + 1] = q1; }
      else        { dot += qa[j] * q0 + qa[j + 1] * q1; }
      int pk2 = __builtin_amdgcn_cvt_pk_fp8_f32(q0 * q0 * FP8SCALE,
                                                q1 * q1 * FP8SCALE, 0, false);
      Tu[j >> 1] = ((uint32_t)pk2 & 0xFFu) | (((uint32_t)pk2 & 0xFF00u) << 8);
    }
  }
  __syncthreads();

  // write-out: 1024 chunks of 16 B in permuted unit order
#pragma unroll
  for (int it = 0; it < 4; ++it) {
    int ch = it * 256 + tid;               // 0..1023
    int t = ch >> 9, d = (ch >> 2) & 127, b16 = ch & 3;
    uint32_t w0 = 0, w1 = 0, w2 = 0, w3 = 0;
#pragma unroll
    for (int r = 0; r < 4; ++r) {
      w0 |= ((uint32_t)T[t][b16 * 8 + r][d] & 0xFFu) << (8 * r);
      w1 |= ((uint32_t)T[t][b16 * 8 + 4 + r][d] & 0xFFu) << (8 * r);
      w2 |= ((uint32_t)T[t][32 + b16 * 8 + r][d] & 0xFFu) << (8 * r);
      w3 |= ((uint32_t)T[t][32 + b16 * 8 + 4 + r][d] & 0xFFu) << (8 * r);
    }
    size_t off = (size_t)t * TSTRB + (size_t)(c * DIM + d) * BATCH +
                 (size_t)bq8 * 64 + b16 * 16;
    uint4 o; o.x = w0; o.y = w1; o.z = w2; o.w = w3;
    *(uint4*)(q2t + off) = o;
  }

#pragma unroll
  for (int off = 1; off < 64; off <<= 1) dot += __shfl_xor(dot, off);
  if (lane == 0) red[w] = dot;
  __syncthreads();
  if (tid == 0) dotPart[blockIdx.y * 8 + blockIdx.x] = red[0] + red[1] + red[2] + red[3];
}

// ---------------------------------------------------------------------------
// Kernel 2: fp8 Gram tile (J,I), J<I, both tensors per block (16 chunks of 64
// K-bytes), 128x128 tile, 4 waves (2x2), 16x16x32 fp8 MFMA. TRIPLE-buffered
// LDS (3 x 16 KB, 3 blocks/CU), depth-2 prefetch, ONE fused barrier per slot.
// Last-done block reduces all partials and writes the final loss.
// ---------------------------------------------------------------------------
__global__ __launch_bounds__(256, 3) void gram_sqrt_kernel(
    const uint8_t* __restrict__ q2t, float* __restrict__ P,
    unsigned int* __restrict__ cnt, float* __restrict__ out) {
  __shared__ uint8_t L[49152 + 16];  // 3 bufs of 16 KB: A@+0, B@+8192

  // ---- pair decode: XCD partition + 8x8 supertile order ----
  int sidx = ((int)blockIdx.x & 7) * 252 + ((int)blockIdx.x >> 3);
  int q = sidx, gi = 0;
  while (q >= 64 * gi + 28) { q -= 64 * gi + 28; ++gi; }
  int I, J;
  if (q < 64 * gi) {
    int gj = q >> 6, r = q & 63;
    I = gi * 8 + (r >> 3);
    J = gj * 8 + (r & 7);
  } else {
    int dq = q - 64 * gi;
    int il = 1;
    while (il * (il + 1) / 2 <= dq) ++il;
    I = gi * 8 + il;
    J = gi * 8 + (dq - il * (il - 1) / 2);
  }

  const uint8_t* baseA = q2t + (size_t)J * (DIM * BATCH);  // 64 KB panels
  const uint8_t* baseB = q2t + (size_t)I * (DIM * BATCH);

  const int tid  = threadIdx.x;
  const int lane = tid & 63, w = tid >> 6;
  const int wm = w & 1, wn = w >> 1;

  // staging: slot t holds (row r=t>>2, phys p=t&3) <- global chunk (p-(r>>1))&3
  const int t0 = tid, t1 = 256 + tid;
  const int r0s = t0 >> 2, r1s = t1 >> 2;
  const int c0s = ((t0 & 3) - ((r0s >> 1) & 3)) & 3;
  const int c1s = ((t1 & 3) - ((r1s >> 1) & 3)) & 3;
  const size_t g0 = (size_t)r0s * BATCH + c0s * 16;
  const size_t g1 = (size_t)r1s * BATCH + c1s * 16;
  uint8_t* Lb = L;
  const int ldsw = w * 1024;   // wave-uniform dest base within a 4 KB round

  // reader: frag-row r = wm*64+i*16+l15, phys chunk (qtr+(l15>>1))&3
  const int l15 = lane & 15, qtr = lane >> 4;
  const int sig = ((qtr + (l15 >> 1)) & 3) * 16;
  const int ApO = wm * 4096 + l15 * 64 + sig;
  const int BpO = 8192 + wn * 4096 + l15 * 64 + sig;

  f32x4 acc[4][4];
#pragma unroll
  for (int i = 0; i < 4; ++i)
#pragma unroll
    for (int j = 0; j < 4; ++j) acc[i][j] = (f32x4){0.f, 0.f, 0.f, 0.f};

  float S0 = 0.f, S1 = 0.f;

  // prologue: stage chunk 0 -> buf0, chunk 1 -> buf1 (order matters for vmcnt)
  ld_lds16(baseA + g0, Lb + ldsw);
  ld_lds16(baseA + g1, Lb + 4096 + ldsw);
  ld_lds16(baseB + g0, Lb + 8192 + ldsw);
  ld_lds16(baseB + g1, Lb + 12288 + ldsw);
  {
    const size_t ck = 64;   // chunk 1
    ld_lds16(baseA + ck + g0, Lb + 16384 + ldsw);
    ld_lds16(baseA + ck + g1, Lb + 16384 + 4096 + ldsw);
    ld_lds16(baseB + ck + g0, Lb + 16384 + 8192 + ldsw);
    ld_lds16(baseB + ck + g1, Lb + 16384 + 12288 + ldsw);
  }

  int beR = 0;                          // read-buffer byte offset (chunk m)
  for (int m = 0; m < 16; ++m) {
    if (m < 15) SYNC_VM4L(); else SYNC_VM0L();

    if (m <= 13) {                      // prefetch chunk m+2 into oldest buf
      const int mi = m + 2;
      int bp = beR + 32768; if (bp >= 49152) bp -= 49152;
      const size_t ck = (size_t)(mi >> 3) * TSTRB + (size_t)(mi & 7) * 64;
      ld_lds16(baseA + ck + g0, Lb + bp + ldsw);
      ld_lds16(baseA + ck + g1, Lb + bp + 4096 + ldsw);
      ld_lds16(baseB + ck + g0, Lb + bp + 8192 + ldsw);
      ld_lds16(baseB + ck + g1, Lb + bp + 12288 + ldsw);
    }

    lx2 a[4], b[4];
#pragma unroll
    for (int i = 0; i < 4; ++i) {       // one b128 per frag-row: both ksteps
      a[i] = *(const lx2*)(Lb + beR + ApO + i * 1024);
      b[i] = *(const lx2*)(Lb + beR + BpO + i * 1024);
    }
#pragma unroll
    for (int i = 0; i < 4; ++i)
#pragma unroll
      for (int j = 0; j < 4; ++j)
        acc[i][j] = __builtin_amdgcn_mfma_f32_16x16x32_fp8_fp8(a[i].x, b[j].x, acc[i][j], 0, 0, 0);
#pragma unroll
    for (int i = 0; i < 4; ++i)
#pragma unroll
      for (int j = 0; j < 4; ++j)
        acc[i][j] = __builtin_amdgcn_mfma_f32_16x16x32_fp8_fp8(a[i].y, b[j].y, acc[i][j], 0, 0, 0);

    if (m == 7) {                       // harvest tensor 0, reset acc
#pragma unroll
      for (int i = 0; i < 4; ++i)
#pragma unroll
        for (int j = 0; j < 4; ++j) {
#pragma unroll
          for (int e = 0; e < 4; ++e) S0 += sqrtf(acc[i][j][e]);
          acc[i][j] = (f32x4){0.f, 0.f, 0.f, 0.f};
        }
    }

    beR += 16384; if (beR >= 49152) beR = 0;
  }

  // harvest tensor 1
#pragma unroll
  for (int i = 0; i < 4; ++i)
#pragma unroll
    for (int j = 0; j < 4; ++j)
#pragma unroll
      for (int e = 0; e < 4; ++e) S1 += sqrtf(acc[i][j][e]);

  // G was scaled by 256*256 -> sqrt scaled by 256
  float local = (S0 + S1) * (1.0f / 256.0f);
#pragma unroll
  for (int off = 1; off < 64; off <<= 1) local += __shfl_xor(local, off);
  float* fred = (float*)(L + 49152);
  if (lane == 0) fred[w] = local;
  __syncthreads();

  __shared__ int lastFlag;
  if (tid == 0) {
    P[512 + blockIdx.x] = fred[0] + fred[1] + fred[2] + fred[3];  // S partial
    __threadfence();                                   // device-scope publish
    lastFlag = (atomicAdd(cnt, 1u) == (unsigned)(NPAIR - 1));
  }
  __syncthreads();

  if (lastFlag) {                       // last-done block: final reduction
    __threadfence();                    // acquire all partials
    float d = 0.f, s = 0.f;
    for (int i = tid; i < 512; i += 256) d += P[i];
    for (int i = tid; i < NPAIR; i += 256) s += P[512 + i];
#pragma unroll
    for (int off = 1; off < 64; off <<= 1) { d += __shfl_xor(d, off); s += __shfl_xor(s, off); }
    if (lane == 0) { fred[w] = d; fred[4 + w] = s; }
    __syncthreads();
    if (tid == 0) {
      float dt = fred[0] + fred[1] + fred[2] + fred[3];
      float st = fred[4] + fred[5] + fred[6] + fred[7];
      out[0] = -dt / 32768.0f - st / (4032.0f * 22.62741699796952f);
    }
  }
}

extern "C" void kernel_launch(void* const* d_in, const int* in_sizes, int n_in,
                              void* d_out, int out_size, void* d_ws, size_t ws_size,
                              hipStream_t stream) {
  const float* emb = (const float*)d_in[0];
  float* out = (float*)d_out;
  // ws layout: [0..3] counter | [64..] 512 dot partials + 2016 S partials
  unsigned int* cnt = (unsigned int*)d_ws;
  float* P = (float*)((char*)d_ws + 64);
  uint8_t* q2t = (uint8_t*)d_ws + 16384;                 // 2 x 8192 x 512 fp8

  hipMemsetAsync(d_ws, 0, 4, stream);                    // zero the counter
  softmax_q2_kernel<<<dim3(8, 64), 256, 0, stream>>>(emb, q2t, P);
  gram_sqrt_kernel<<<dim3(NPAIR), 256, 0, stream>>>(q2t, P, cnt, out);
}

// Round 7
// 133.736 us; speedup vs baseline: 1.3171x; 1.3171x over previous
//
#include <hip/hip_runtime.h>
#include <cstdint>
#include <cstddef>

// Problem constants
#define NCLUS 64
#define DIM   128
#define BATCH 512              // K of the Gram reduction (bytes per fp8 row)
#define QCOLS 8192             // NCLUS*DIM
#define NPAIR 2016             // 64*63/2
#define TSTRB (QCOLS * BATCH)  // BYTES per tensor in fp8 (4,194,304)
#define FP8SCALE 256.0f        // q^2 * 256 -> e4m3 (max 256 < 448, no clip)

typedef float f32x4 __attribute__((ext_vector_type(4)));
typedef long  lx2  __attribute__((ext_vector_type(2)));

// q2t layout: row (t, c*128+d) of 512 bytes over b. Within each 64-byte
// k-chunk, 8-byte units are PERMUTED: global unit u stored at p=(u&3)*2+(u>>2),
// so one 16-B LDS chunk = both ksteps of one MFMA-quarter (ds_read_b128).

__device__ __forceinline__ void ld_lds16(const void* g, void* l) {
  __builtin_amdgcn_global_load_lds(
      (__attribute__((address_space(1))) void*)g,
      (__attribute__((address_space(3))) void*)l, 16, 0, 0);
}

#define SYNC_VM4()  asm volatile("s_waitcnt vmcnt(4)\n\ts_barrier" ::: "memory")
#define SYNC_VM0()  asm volatile("s_waitcnt vmcnt(0)\n\ts_barrier" ::: "memory")
#define SYNC_LGKM() asm volatile("s_waitcnt lgkmcnt(0)\n\ts_barrier" ::: "memory")

// ---------------------------------------------------------------------------
// Kernel 1: softmax over D=128 -> q^2*256 -> fp8 e4m3 -> permuted-transposed
// q2t. COALESCED reads: one 32-lane group per softmax row; lane reads float4
// at col=(lane&31) -> each load covers two contiguous 512-B row segments.
// Block (bq in 0..7, c in 0..63): 64 b x 2 tensors = 128 rows, 16 iters of
// 8 rows (2 per wave). t=0/t=1 of the same b on consecutive iters -> dot in 4
// registers. LDS: u32 tile T32[2][64][33] (pad -> conflict-light).
// ---------------------------------------------------------------------------
__global__ __launch_bounds__(256) void softmax_q2_kernel(
    const float* __restrict__ emb, uint8_t* __restrict__ q2t,
    float* __restrict__ dotPart) {
  __shared__ uint32_t T32[2 * 64 * 33];      // 16.5 KB; [t*64+b][col] stride 33
  __shared__ float red[4];
  const int c  = blockIdx.y;
  const int bq = blockIdx.x;
  const int tid = threadIdx.x;
  const int w = tid >> 6, lane = tid & 63;
  const int sub = lane >> 5;                 // which of the 2 rows this iter
  const int col = lane & 31;                 // float4 index within the row

  float4 qa = {0.f, 0.f, 0.f, 0.f};
  float dot = 0.f;

#pragma unroll
  for (int k = 0; k < 16; ++k) {
    const int t  = k & 1;
    const int bl = w * 16 + (k >> 1) * 2 + sub;   // 0..63
    const int b  = bq * 64 + bl;
    const float4 v = *(const float4*)(emb +
        ((size_t)(t * BATCH + b) * QCOLS + (size_t)c * DIM + col * 4));

    float mx = fmaxf(fmaxf(v.x, v.y), fmaxf(v.z, v.w));
#pragma unroll
    for (int off = 1; off < 32; off <<= 1) mx = fmaxf(mx, __shfl_xor(mx, off));
    float e0 = __expf(v.x - mx), e1 = __expf(v.y - mx);
    float e2 = __expf(v.z - mx), e3 = __expf(v.w - mx);
    float s = (e0 + e1) + (e2 + e3);
#pragma unroll
    for (int off = 1; off < 32; off <<= 1) s += __shfl_xor(s, off);
    const float inv = 1.0f / s;
    const float q0 = e0 * inv, q1 = e1 * inv, q2 = e2 * inv, q3 = e3 * inv;

    if (t == 0) { qa.x = q0; qa.y = q1; qa.z = q2; qa.w = q3; }
    else        { dot += qa.x * q0 + qa.y * q1 + qa.z * q2 + qa.w * q3; }

    int pk = __builtin_amdgcn_cvt_pk_fp8_f32(q0 * q0 * FP8SCALE,
                                             q1 * q1 * FP8SCALE, 0, false);
    pk = __builtin_amdgcn_cvt_pk_fp8_f32(q2 * q2 * FP8SCALE,
                                         q3 * q3 * FP8SCALE, pk, true);
    T32[(t * 64 + bl) * 33 + col] = (uint32_t)pk;
  }
  __syncthreads();

  // write-out: 1024 chunks of 16 B in permuted unit order; byte for
  // (t,row,d) = byte (d&3) of T32[(t*64+row)*33 + (d>>2)].
#pragma unroll
  for (int it = 0; it < 4; ++it) {
    int ch = it * 256 + tid;               // 0..1023
    int t = ch >> 9, d = (ch >> 2) & 127, b16 = ch & 3;
    const int dq = d >> 2, sh = (d & 3) * 8;
    uint32_t w0 = 0, w1 = 0, w2 = 0, w3 = 0;
#pragma unroll
    for (int r = 0; r < 4; ++r) {
      w0 |= ((T32[(t * 64 + b16 * 8 + r) * 33 + dq] >> sh) & 0xFFu) << (8 * r);
      w1 |= ((T32[(t * 64 + b16 * 8 + 4 + r) * 33 + dq] >> sh) & 0xFFu) << (8 * r);
      w2 |= ((T32[(t * 64 + 32 + b16 * 8 + r) * 33 + dq] >> sh) & 0xFFu) << (8 * r);
      w3 |= ((T32[(t * 64 + 32 + b16 * 8 + 4 + r) * 33 + dq] >> sh) & 0xFFu) << (8 * r);
    }
    size_t off = (size_t)t * TSTRB + (size_t)(c * DIM + d) * BATCH +
                 (size_t)bq * 64 + b16 * 16;
    uint4 o; o.x = w0; o.y = w1; o.z = w2; o.w = w3;
    *(uint4*)(q2t + off) = o;
  }

#pragma unroll
  for (int off = 1; off < 64; off <<= 1) dot += __shfl_xor(dot, off);
  if (lane == 0) red[w] = dot;
  __syncthreads();
  if (tid == 0) dotPart[blockIdx.y * 8 + blockIdx.x] = red[0] + red[1] + red[2] + red[3];
}

// ---------------------------------------------------------------------------
// Kernel 2: fp8 Gram tile (J,I), J<I, both tensors per block (16 chunks of 64
// K-bytes), 128x128 tile, 4 waves (2x2), 16x16x32 fp8 MFMA, double-buffered
// LDS (2 x 16 KB, 4 blocks/CU) with one-chunk-ahead prefetch (vmcnt(4)).
// Reader: ONE ds_read_b128 per frag-row = both ksteps (permuted layout);
// conflict-free (verified 0 in R5). XCD supertile pair ordering.
// ---------------------------------------------------------------------------
__global__ __launch_bounds__(256, 4) void gram_sqrt_kernel(
    const uint8_t* __restrict__ q2t, float* __restrict__ Spart) {
  __shared__ uint8_t L[32768 + 16];  // buf0 A@0 B@8192, buf1 A@16384 B@24576

  // ---- pair decode: XCD partition + 8x8 supertile order ----
  int sidx = ((int)blockIdx.x & 7) * 252 + ((int)blockIdx.x >> 3);
  int q = sidx, gi = 0;
  while (q >= 64 * gi + 28) { q -= 64 * gi + 28; ++gi; }
  int I, J;
  if (q < 64 * gi) {
    int gj = q >> 6, r = q & 63;
    I = gi * 8 + (r >> 3);
    J = gj * 8 + (r & 7);
  } else {
    int dq = q - 64 * gi;
    int il = 1;
    while (il * (il + 1) / 2 <= dq) ++il;
    I = gi * 8 + il;
    J = gi * 8 + (dq - il * (il - 1) / 2);
  }

  const uint8_t* baseA = q2t + (size_t)J * (DIM * BATCH);  // 64 KB panels
  const uint8_t* baseB = q2t + (size_t)I * (DIM * BATCH);

  const int tid  = threadIdx.x;
  const int lane = tid & 63, w = tid >> 6;
  const int wm = w & 1, wn = w >> 1;

  // staging: slot t holds (row r=t>>2, phys p=t&3) <- global chunk (p-(r>>1))&3
  const int t0 = tid, t1 = 256 + tid;
  const int r0s = t0 >> 2, r1s = t1 >> 2;
  const int c0s = ((t0 & 3) - ((r0s >> 1) & 3)) & 3;
  const int c1s = ((t1 & 3) - ((r1s >> 1) & 3)) & 3;
  const size_t g0 = (size_t)r0s * BATCH + c0s * 16;
  const size_t g1 = (size_t)r1s * BATCH + c1s * 16;
  uint8_t* Lb = L;
  const int ldsw = w * 1024;   // wave-uniform dest base within a 4 KB round

  // reader: frag-row r = wm*64+i*16+l15, phys chunk (qtr+(l15>>1))&3
  const int l15 = lane & 15, qtr = lane >> 4;
  const int sig = ((qtr + (l15 >> 1)) & 3) * 16;
  const int ApO = wm * 4096 + l15 * 64 + sig;
  const int BpO = 8192 + wn * 4096 + l15 * 64 + sig;

  f32x4 acc[4][4];
#pragma unroll
  for (int i = 0; i < 4; ++i)
#pragma unroll
    for (int j = 0; j < 4; ++j) acc[i][j] = (f32x4){0.f, 0.f, 0.f, 0.f};

  float S0 = 0.f, S1 = 0.f;

  // prologue: stage chunk 0 into buf0
  ld_lds16(baseA + g0, Lb + ldsw);
  ld_lds16(baseA + g1, Lb + 4096 + ldsw);
  ld_lds16(baseB + g0, Lb + 8192 + ldsw);
  ld_lds16(baseB + g1, Lb + 12288 + ldsw);

  for (int m = 0; m < 16; ++m) {
    if (m < 15) {                       // prefetch chunk m+1 into buf (m+1)&1
      const int mi = m + 1;
      const int bb = (mi & 1) << 14;
      const size_t ck = (size_t)(mi >> 3) * TSTRB + (size_t)(mi & 7) * 64;
      ld_lds16(baseA + ck + g0, Lb + bb + ldsw);
      ld_lds16(baseA + ck + g1, Lb + bb + 4096 + ldsw);
      ld_lds16(baseB + ck + g0, Lb + bb + 8192 + ldsw);
      ld_lds16(baseB + ck + g1, Lb + bb + 12288 + ldsw);
      SYNC_VM4();                       // oldest 4 (= chunk m) have landed
    } else {
      SYNC_VM0();
    }

    const int be = (m & 1) << 14;
    lx2 a[4], b[4];
#pragma unroll
    for (int i = 0; i < 4; ++i) {       // one b128 per frag-row: both ksteps
      a[i] = *(const lx2*)(Lb + be + ApO + i * 1024);
      b[i] = *(const lx2*)(Lb + be + BpO + i * 1024);
    }
#pragma unroll
    for (int i = 0; i < 4; ++i)
#pragma unroll
      for (int j = 0; j < 4; ++j)
        acc[i][j] = __builtin_amdgcn_mfma_f32_16x16x32_fp8_fp8(a[i].x, b[j].x, acc[i][j], 0, 0, 0);
#pragma unroll
    for (int i = 0; i < 4; ++i)
#pragma unroll
      for (int j = 0; j < 4; ++j)
        acc[i][j] = __builtin_amdgcn_mfma_f32_16x16x32_fp8_fp8(a[i].y, b[j].y, acc[i][j], 0, 0, 0);

    if (m == 7) {                       // harvest tensor 0, reset acc
#pragma unroll
      for (int i = 0; i < 4; ++i)
#pragma unroll
        for (int j = 0; j < 4; ++j) {
#pragma unroll
          for (int e = 0; e < 4; ++e) S0 += sqrtf(acc[i][j][e]);
          acc[i][j] = (f32x4){0.f, 0.f, 0.f, 0.f};
        }
    }

    SYNC_LGKM();                        // buf(m&1) reads done before overwrite
  }

  // harvest tensor 1
#pragma unroll
  for (int i = 0; i < 4; ++i)
#pragma unroll
    for (int j = 0; j < 4; ++j)
#pragma unroll
      for (int e = 0; e < 4; ++e) S1 += sqrtf(acc[i][j][e]);

  // G was scaled by 256*256 -> sqrt scaled by 256
  float local = (S0 + S1) * (1.0f / 256.0f);
#pragma unroll
  for (int off = 1; off < 64; off <<= 1) local += __shfl_xor(local, off);
  float* fred = (float*)(L + 32768);
  if (lane == 0) fred[w] = local;
  __syncthreads();
  if (tid == 0) Spart[blockIdx.x] = fred[0] + fred[1] + fred[2] + fred[3];
}

// ---------------------------------------------------------------------------
// Kernel 3: reduce partials and combine.
// P[0..511] = dot partials, P[512..2527] = S partials.
// loss = -dot/(B*N_C) - S/((N_C^2-N_C)*sqrt(B))
// ---------------------------------------------------------------------------
__global__ __launch_bounds__(256) void finalize_kernel(
    const float* __restrict__ P, float* __restrict__ out) {
  __shared__ float rd[8];
  const int tid = threadIdx.x;
  float d = 0.f, s = 0.f;
  for (int i = tid; i < 512; i += 256) d += P[i];
  for (int i = tid; i < NPAIR; i += 256) s += P[512 + i];
#pragma unroll
  for (int off = 1; off < 64; off <<= 1) { d += __shfl_xor(d, off); s += __shfl_xor(s, off); }
  const int w = tid >> 6;
  if ((tid & 63) == 0) { rd[w] = d; rd[4 + w] = s; }
  __syncthreads();
  if (tid == 0) {
    float dt = rd[0] + rd[1] + rd[2] + rd[3];
    float st = rd[4] + rd[5] + rd[6] + rd[7];
    out[0] = -dt / 32768.0f - st / (4032.0f * 22.62741699796952f);
  }
}

extern "C" void kernel_launch(void* const* d_in, const int* in_sizes, int n_in,
                              void* d_out, int out_size, void* d_ws, size_t ws_size,
                              hipStream_t stream) {
  const float* emb = (const float*)d_in[0];
  float* out = (float*)d_out;
  float* P = (float*)d_ws;                                 // 2528 partials
  uint8_t* q2t = (uint8_t*)d_ws + 16384;                   // 2 x 8192 x 512 fp8

  softmax_q2_kernel<<<dim3(8, 64), 256, 0, stream>>>(emb, q2t, P);
  gram_sqrt_kernel<<<dim3(NPAIR), 256, 0, stream>>>(q2t, P + 512);
  finalize_kernel<<<1, 256, 0, stream>>>(P, out);
}